// Round 2
// baseline (631.900 us; speedup 1.0000x reference)
//
#include <hip/hip_runtime.h>
#include <math.h>

#define S_DIM 1024
#define B_DIM 16
#define K_DIM 1024
#define QD_DIM 1024
#define KD_DIM 1024
#define MASK_NEG (-3.0e38f)

using short8v = __attribute__((ext_vector_type(8))) short;
using float4v = __attribute__((ext_vector_type(4))) float;

#define MFMA(a, b, c) __builtin_amdgcn_mfma_f32_16x16x32_bf16(a, b, c, 0, 0, 0)

// ---------------------------------------------------------------------------
// helpers
// ---------------------------------------------------------------------------

// async global->LDS, 16 B per lane, dest = uniform base + lane*16 (linear)
__device__ __forceinline__ void gll16(const void* g, void* l) {
    __builtin_amdgcn_global_load_lds((const __attribute__((address_space(1))) unsigned int*)g,
                                     (__attribute__((address_space(3))) unsigned int*)l,
                                     16, 0, 0);
}

// fp32x4 -> bf16 hi (truncate) + bf16 of residual (truncate). Bit-identical to
// the previously-passing split4.
__device__ __forceinline__ void split4(const float4 v, uint2& hi, uint2& lo) {
    uint ax = __float_as_uint(v.x), ay = __float_as_uint(v.y);
    uint az = __float_as_uint(v.z), aw = __float_as_uint(v.w);
    hi.x = __builtin_amdgcn_perm(ay, ax, 0x07060302u);
    hi.y = __builtin_amdgcn_perm(aw, az, 0x07060302u);
    float rx = v.x - __uint_as_float(ax & 0xFFFF0000u);
    float ry = v.y - __uint_as_float(ay & 0xFFFF0000u);
    float rz = v.z - __uint_as_float(az & 0xFFFF0000u);
    float rw = v.w - __uint_as_float(aw & 0xFFFF0000u);
    lo.x = __builtin_amdgcn_perm(__float_as_uint(ry), __float_as_uint(rx), 0x07060302u);
    lo.y = __builtin_amdgcn_perm(__float_as_uint(rw), __float_as_uint(rz), 0x07060302u);
}

// Stage a 128x32 bf16 tile (rows [row0,row0+128), cols [k0,k0+32) of a
// row-major [*][1024] bf16 plane) into linear LDS [128][32] via global_load_lds.
// Wave w covers LDS rows w*32 .. w*32+31 (two 1024-B segments, exact fit).
__device__ __forceinline__ void stage_tile(const short* __restrict__ gplane, int row0, int k0,
                                           short* lds, int w, int lane) {
    const short* g0 = gplane + (size_t)(row0 + w * 32 + (lane >> 2)) * 1024 + k0 + (lane & 3) * 8;
    gll16(g0, lds + w * 1024);
    gll16(g0 + 16 * 1024, lds + w * 1024 + 512);
}

// One BK=32 step of the 3-term split-bf16 MFMA: acc += Ah*Bh + Al*Bh + Ah*Bl
__device__ __forceinline__ void mfma_step(const short* __restrict__ Ah, const short* __restrict__ Al,
                                          const short* __restrict__ Bh, const short* __restrict__ Bl,
                                          int wm, int wn, int quad, int l15, float4v (&acc)[4][4]) {
    short8v ah[4], al[4];
    #pragma unroll
    for (int mt = 0; mt < 4; ++mt) {
        const int off = (wm * 64 + mt * 16 + l15) * 32 + quad * 8;
        ah[mt] = *(const short8v*)(Ah + off);
        al[mt] = *(const short8v*)(Al + off);
    }
    #pragma unroll
    for (int nt = 0; nt < 4; ++nt) {
        const int off = (wn * 64 + nt * 16 + l15) * 32 + quad * 8;
        short8v bh = *(const short8v*)(Bh + off);
        short8v bl = *(const short8v*)(Bl + off);
        #pragma unroll
        for (int mt = 0; mt < 4; ++mt) acc[mt][nt] = MFMA(ah[mt], bh, acc[mt][nt]);
        #pragma unroll
        for (int mt = 0; mt < 4; ++mt) acc[mt][nt] = MFMA(al[mt], bh, acc[mt][nt]);
        #pragma unroll
        for (int mt = 0; mt < 4; ++mt) acc[mt][nt] = MFMA(ah[mt], bl, acc[mt][nt]);
    }
}

// ---------------------------------------------------------------------------
// prep: fp32 [R][1024] -> bf16 hi/lo row-major streams (flat). grid = R blocks.
// ---------------------------------------------------------------------------
__global__ __launch_bounds__(256) void k_split(const float* __restrict__ src,
                                               short* __restrict__ h, short* __restrict__ l) {
    const size_t base = ((size_t)blockIdx.x * 256 + threadIdx.x) * 4;
    const float4 v = *(const float4*)(src + base);
    uint2 hh, ll;
    split4(v, hh, ll);
    *(uint2*)(h + base) = hh;
    *(uint2*)(l + base) = ll;
}

// ---------------------------------------------------------------------------
// prep: keys [b][k][d] -> KT hi/lo [b][d][k] bf16. grid (32 d-tiles, 32 k-tiles, B)
// ---------------------------------------------------------------------------
__global__ __launch_bounds__(256) void k_transpose(const float* __restrict__ keys,
                                                   short* __restrict__ th, short* __restrict__ tl) {
    __shared__ float T[32][33];
    const int t = threadIdx.x;
    const int b = blockIdx.z, d0 = blockIdx.x * 32, k0 = blockIdx.y * 32;
    const float* Kb = keys + (size_t)b * K_DIM * KD_DIM;
    const int ry = t >> 3, cx = (t & 7) * 4;
    const float4 v = *(const float4*)(Kb + (size_t)(k0 + ry) * KD_DIM + d0 + cx);
    T[ry][cx] = v.x; T[ry][cx + 1] = v.y; T[ry][cx + 2] = v.z; T[ry][cx + 3] = v.w;
    __syncthreads();
    float4 g;
    g.x = T[cx][ry]; g.y = T[cx + 1][ry]; g.z = T[cx + 2][ry]; g.w = T[cx + 3][ry];
    uint2 hh, ll;
    split4(g, hh, ll);
    const size_t o = (size_t)b * K_DIM * KD_DIM + (size_t)(d0 + ry) * K_DIM + k0 + cx;
    *(uint2*)(th + o) = hh;
    *(uint2*)(tl + o) = ll;
}

// ---------------------------------------------------------------------------
// GEMM1: TQ[m][n] = sum_k Q[m][k]*W[n][k]; A manual split from fp32 Q,
// B via global_load_lds from pre-split W streams. Epilogue: TQ -> bf16 hi/lo
// planes [b][s][d] for g2's A.
// ---------------------------------------------------------------------------
__global__ __launch_bounds__(256) void g1k(const float* __restrict__ Q,
                                           const short* __restrict__ Wh, const short* __restrict__ Wl,
                                           short* __restrict__ TQh, short* __restrict__ TQl) {
    __shared__ __align__(16) short Ah[128 * 32], Al[128 * 32], Bh[128 * 32], Bl[128 * 32];
    const int t = threadIdx.x, lane = t & 63, w = t >> 6;
    const int wm = w >> 1, wn = w & 1, quad = lane >> 4, l15 = lane & 15;
    const int m0 = blockIdx.y * 128, n0 = blockIdx.x * 128;
    const int sr = t >> 3, sc = (t & 7) * 4;

    float4v acc[4][4] = {};

    for (int k0 = 0; k0 < QD_DIM; k0 += 32) {
        stage_tile(Wh, n0, k0, Bh, w, lane);      // async B first
        stage_tile(Wl, n0, k0, Bl, w, lane);
        #pragma unroll
        for (int i = 0; i < 4; ++i) {             // manual A: split Q on the fly
            const int r = sr + i * 32;
            const float4 va = *(const float4*)(Q + (size_t)(m0 + r) * QD_DIM + k0 + sc);
            uint2 h, l;
            split4(va, h, l);
            *(uint2*)&Ah[r * 32 + sc] = h;
            *(uint2*)&Al[r * 32 + sc] = l;
        }
        __syncthreads();
        mfma_step(Ah, Al, Bh, Bl, wm, wn, quad, l15, acc);
        __syncthreads();
    }
    #pragma unroll
    for (int mt = 0; mt < 4; ++mt)
        #pragma unroll
        for (int reg = 0; reg < 4; ++reg) {
            const int m = m0 + wm * 64 + mt * 16 + quad * 4 + reg;
            const int s = m >> 4, bq = m & 15;
            short* th = TQh + (size_t)bq * (1024 * 1024) + (size_t)s * 1024;
            short* tl = TQl + (size_t)bq * (1024 * 1024) + (size_t)s * 1024;
            #pragma unroll
            for (int nt = 0; nt < 4; ++nt) {
                const int n = n0 + wn * 64 + nt * 16 + l15;
                const float x = acc[mt][nt][reg];
                const uint u = __float_as_uint(x);
                th[n] = (short)(u >> 16);
                const float r2 = x - __uint_as_float(u & 0xFFFF0000u);
                tl[n] = (short)(__float_as_uint(r2) >> 16);
            }
        }
}

// ---------------------------------------------------------------------------
// GEMM2 (per b): alpha[s][b][k] = sum_d TQ[b][s][d]*keys[b][k][d], + mask.
// All four operand streams via global_load_lds.
// ---------------------------------------------------------------------------
__global__ __launch_bounds__(256) void g2k(const short* __restrict__ TQh, const short* __restrict__ TQl,
                                           const short* __restrict__ Kh, const short* __restrict__ Kl,
                                           const int* __restrict__ mask, float* __restrict__ alpha) {
    __shared__ __align__(16) short Ah[128 * 32], Al[128 * 32], Bh[128 * 32], Bl[128 * 32];
    const int t = threadIdx.x, lane = t & 63, w = t >> 6;
    const int wm = w >> 1, wn = w & 1, quad = lane >> 4, l15 = lane & 15;
    const int m0 = blockIdx.y * 128, n0 = blockIdx.x * 128, b = blockIdx.z;
    const short* Ahp = TQh + (size_t)b * (1024 * 1024);
    const short* Alp = TQl + (size_t)b * (1024 * 1024);
    const short* Bhp = Kh + (size_t)b * (1024 * 1024);
    const short* Blp = Kl + (size_t)b * (1024 * 1024);

    float4v acc[4][4] = {};

    for (int k0 = 0; k0 < KD_DIM; k0 += 32) {
        stage_tile(Ahp, m0, k0, Ah, w, lane);
        stage_tile(Alp, m0, k0, Al, w, lane);
        stage_tile(Bhp, n0, k0, Bh, w, lane);
        stage_tile(Blp, n0, k0, Bl, w, lane);
        __syncthreads();
        mfma_step(Ah, Al, Bh, Bl, wm, wn, quad, l15, acc);
        __syncthreads();
    }
    int mk[4];
    #pragma unroll
    for (int nt = 0; nt < 4; ++nt)
        mk[nt] = mask[b * K_DIM + n0 + wn * 64 + nt * 16 + l15];
    #pragma unroll
    for (int mt = 0; mt < 4; ++mt)
        #pragma unroll
        for (int reg = 0; reg < 4; ++reg) {
            const int m = m0 + wm * 64 + mt * 16 + quad * 4 + reg;
            #pragma unroll
            for (int nt = 0; nt < 4; ++nt) {
                const int n = n0 + wn * 64 + nt * 16 + l15;
                alpha[((size_t)m * B_DIM + b) * K_DIM + n] = mk[nt] ? MASK_NEG : acc[mt][nt][reg];
            }
        }
}

// ---------------------------------------------------------------------------
// Softmax stats per row r = s*B+b (unchanged from passing kernel)
// ---------------------------------------------------------------------------
__global__ __launch_bounds__(256) void k_stats(const float* __restrict__ alpha,
                                               float* __restrict__ mx,
                                               float* __restrict__ il) {
    const int r = blockIdx.x;
    const int t = threadIdx.x;
    const float4 v = ((const float4*)(alpha + (size_t)r * K_DIM))[t];
    float m = fmaxf(fmaxf(v.x, v.y), fmaxf(v.z, v.w));
    #pragma unroll
    for (int o = 1; o < 64; o <<= 1) m = fmaxf(m, __shfl_xor(m, o, 64));
    __shared__ float redm[4];
    __shared__ float reds[4];
    const int wid = t >> 6;
    if ((t & 63) == 0) redm[wid] = m;
    __syncthreads();
    const float M = fmaxf(fmaxf(redm[0], redm[1]), fmaxf(redm[2], redm[3]));
    float s = expf(v.x - M) + expf(v.y - M) + expf(v.z - M) + expf(v.w - M);
    #pragma unroll
    for (int o = 1; o < 64; o <<= 1) s += __shfl_xor(s, o, 64);
    if ((t & 63) == 0) reds[wid] = s;
    __syncthreads();
    if (t == 0) {
        mx[r] = M;
        il[r] = 1.0f / (reds[0] + reds[1] + reds[2] + reds[3]);
    }
}

// ---------------------------------------------------------------------------
// GEMM3 (per b): out[s][b][d] = sum_k P[s][k]*keys[b][k][d].
// A = P on the fly (exp + split); B via global_load_lds from pre-transposed KT.
// ---------------------------------------------------------------------------
__global__ __launch_bounds__(256) void g3k(const float* __restrict__ alpha,
                                           const short* __restrict__ KTh, const short* __restrict__ KTl,
                                           const float* __restrict__ mx, const float* __restrict__ il,
                                           float* __restrict__ outk) {
    __shared__ __align__(16) short Ah[128 * 32], Al[128 * 32], Bh[128 * 32], Bl[128 * 32];
    __shared__ float Ms[128], Ls[128];
    const int t = threadIdx.x, lane = t & 63, w = t >> 6;
    const int wm = w >> 1, wn = w & 1, quad = lane >> 4, l15 = lane & 15;
    const int m0 = blockIdx.y * 128, n0 = blockIdx.x * 128, b = blockIdx.z;
    const int sr = t >> 3, sc = (t & 7) * 4;
    const short* Bhp = KTh + (size_t)b * (1024 * 1024);
    const short* Blp = KTl + (size_t)b * (1024 * 1024);

    if (t < 128) {
        Ms[t] = mx[(size_t)(m0 + t) * B_DIM + b];
        Ls[t] = il[(size_t)(m0 + t) * B_DIM + b];
    }
    __syncthreads();

    float4v acc[4][4] = {};

    for (int k0 = 0; k0 < K_DIM; k0 += 32) {
        stage_tile(Bhp, n0, k0, Bh, w, lane);     // async B first
        stage_tile(Blp, n0, k0, Bl, w, lane);
        #pragma unroll
        for (int i = 0; i < 4; ++i) {             // manual A: P = exp(alpha-M)*il
            const int r = sr + i * 32;
            const float4 va = *(const float4*)(alpha + ((size_t)(m0 + r) * B_DIM + b) * K_DIM + k0 + sc);
            const float Mv = Ms[r], Lv = Ls[r];
            float4 p;
            p.x = __expf(va.x - Mv) * Lv;
            p.y = __expf(va.y - Mv) * Lv;
            p.z = __expf(va.z - Mv) * Lv;
            p.w = __expf(va.w - Mv) * Lv;
            uint2 h, l;
            split4(p, h, l);
            *(uint2*)&Ah[r * 32 + sc] = h;
            *(uint2*)&Al[r * 32 + sc] = l;
        }
        __syncthreads();
        mfma_step(Ah, Al, Bh, Bl, wm, wn, quad, l15, acc);
        __syncthreads();
    }
    #pragma unroll
    for (int mt = 0; mt < 4; ++mt)
        #pragma unroll
        for (int reg = 0; reg < 4; ++reg) {
            const int m = m0 + wm * 64 + mt * 16 + quad * 4 + reg;
            #pragma unroll
            for (int nt = 0; nt < 4; ++nt) {
                const int n = n0 + wn * 64 + nt * 16 + l15;
                outk[((size_t)m * B_DIM + b) * KD_DIM + n] = acc[mt][nt][reg];
            }
        }
}

// final copy (only for the small-workspace alias layout)
__global__ __launch_bounds__(256) void k_copy(const float4* __restrict__ src, float4* __restrict__ dst) {
    const size_t i = (size_t)blockIdx.x * 256 + threadIdx.x;
    dst[i] = src[i];
}

// ---------------------------------------------------------------------------
extern "C" void kernel_launch(void* const* d_in, const int* in_sizes, int n_in,
                              void* d_out, int out_size, void* d_ws, size_t ws_size,
                              hipStream_t stream) {
    const float* Q    = (const float*)d_in[0];   // (S, B, QD)
    const float* keys = (const float*)d_in[1];   // (B, K, KD)
    const int*   mask = (const int*)d_in[2];     // (B, K)
    const float* W    = (const float*)d_in[3];   // (KD, QD)

    float* out_att   = (float*)d_out;
    float* out_alpha = out_att + (size_t)S_DIM * B_DIM * KD_DIM;

    const size_t PL     = (size_t)1024 * 1024;   // shorts per W stream (2 MiB)
    const size_t STREAM = (size_t)B_DIM * PL;    // shorts per big stream (32 MiB)

    short *Wh, *Wl, *Khs, *Kls, *KTh, *KTl, *TQh, *TQl;
    float *mx, *il, *g3out;
    bool small_ws;
    char* ws = (char*)d_ws;

    if (ws_size >= ((size_t)197 << 20)) {
        // roomy workspace: everything lives in ws, no aliasing, no final copy
        small_ws = false;
        Wh  = (short*)ws;
        Wl  = Wh + PL;
        Khs = Wl + PL;
        Kls = Khs + STREAM;
        KTh = Kls + STREAM;
        KTl = KTh + STREAM;
        TQh = KTl + STREAM;
        TQl = TQh + STREAM;
        mx  = (float*)(TQl + STREAM);
        il  = mx + S_DIM * B_DIM;
        g3out = out_att;
    } else {
        // proven-safe layout: ws use = 64 MiB + 128 KiB (same as prior session).
        // d_out regions are used as sequenced scratch:
        //   alpha region:  Wh/Wl until g2 overwrites it with real alpha
        //   attened region: Kh/Kl (prep->g2), then KTh/KTl (->g3), then final copy
        small_ws = true;
        TQh = (short*)ws;
        TQl = TQh + STREAM;
        mx  = (float*)(TQl + STREAM);
        il  = mx + S_DIM * B_DIM;
        Wh  = (short*)out_alpha;
        Wl  = Wh + PL;
        Khs = (short*)out_att;
        Kls = Khs + STREAM;
        KTh = Khs;          // sequential reuse of the same region (after g2)
        KTl = Kls;
        g3out = (float*)ws; // reuse TQ region (dead after g2)
    }

    dim3 blk(256);

    k_split<<<dim3(KD_DIM), blk, 0, stream>>>(W, Wh, Wl);                       // 1024 blocks
    k_split<<<dim3(B_DIM * K_DIM), blk, 0, stream>>>(keys, Khs, Kls);           // 16384 blocks

    g1k<<<dim3(KD_DIM / 128, (S_DIM * B_DIM) / 128), blk, 0, stream>>>(Q, Wh, Wl, TQh, TQl);

    g2k<<<dim3(K_DIM / 128, S_DIM / 128, B_DIM), blk, 0, stream>>>(TQh, TQl, Khs, Kls, mask, out_alpha);

    k_transpose<<<dim3(32, 32, B_DIM), blk, 0, stream>>>(keys, KTh, KTl);       // after g2 (aliases K streams)

    k_stats<<<dim3(S_DIM * B_DIM), blk, 0, stream>>>(out_alpha, mx, il);

    g3k<<<dim3(KD_DIM / 128, S_DIM / 128, B_DIM), blk, 0, stream>>>(out_alpha, KTh, KTl, mx, il, g3out);

    if (small_ws)
        k_copy<<<dim3((S_DIM * B_DIM * KD_DIM) / (4 * 256)), blk, 0, stream>>>((const float4*)g3out,
                                                                               (float4*)out_att);
}

// Round 3
// 556.536 us; speedup vs baseline: 1.1354x; 1.1354x over previous
//
#include <hip/hip_runtime.h>
#include <math.h>

#define S_DIM 1024
#define B_DIM 16
#define K_DIM 1024
#define QD_DIM 1024
#define KD_DIM 1024
#define MASK_NEG (-3.0e38f)

using short8v = __attribute__((ext_vector_type(8))) short;
using float4v = __attribute__((ext_vector_type(4))) float;
using uint4v  = __attribute__((ext_vector_type(4))) uint;

#define MFMA(a, b, c) __builtin_amdgcn_mfma_f32_16x16x32_bf16(a, b, c, 0, 0, 0)
#define BAR()   __builtin_amdgcn_s_barrier()
#define SB0()   __builtin_amdgcn_sched_barrier(0)
#define PRIO(x) __builtin_amdgcn_s_setprio(x)
#define VMCNT(N) asm volatile("s_waitcnt vmcnt(" #N ")" ::: "memory")
#define LGKM0()  asm volatile("s_waitcnt lgkmcnt(0)" ::: "memory")

// ---------------------------------------------------------------------------
// helpers
// ---------------------------------------------------------------------------

// async global->LDS, 16 B per lane, dest = uniform base + lane*16 (linear)
__device__ __forceinline__ void gll16(const void* g, void* l) {
    __builtin_amdgcn_global_load_lds((const __attribute__((address_space(1))) unsigned int*)g,
                                     (__attribute__((address_space(3))) unsigned int*)l,
                                     16, 0, 0);
}

// fp32x4 -> bf16 hi (truncate) + bf16 of residual (truncate).
__device__ __forceinline__ void split4(const float4 v, uint2& hi, uint2& lo) {
    uint ax = __float_as_uint(v.x), ay = __float_as_uint(v.y);
    uint az = __float_as_uint(v.z), aw = __float_as_uint(v.w);
    hi.x = __builtin_amdgcn_perm(ay, ax, 0x07060302u);
    hi.y = __builtin_amdgcn_perm(aw, az, 0x07060302u);
    float rx = v.x - __uint_as_float(ax & 0xFFFF0000u);
    float ry = v.y - __uint_as_float(ay & 0xFFFF0000u);
    float rz = v.z - __uint_as_float(az & 0xFFFF0000u);
    float rw = v.w - __uint_as_float(aw & 0xFFFF0000u);
    lo.x = __builtin_amdgcn_perm(__float_as_uint(ry), __float_as_uint(rx), 0x07060302u);
    lo.y = __builtin_amdgcn_perm(__float_as_uint(rw), __float_as_uint(rz), 0x07060302u);
}

// LDS tile layout: 256 rows x 32 shorts (16 KB), slot = 16B unit = (row*4 + c).
// Swizzle f(s) = s ^ ((s>>2)&7)  (bits 0-2 flipped by bits 2-4).
// Reads use f(slot); gll16 writes linearly, so the GLOBAL source of dest slot D
// is the inverse slot: s0=D0^D2^D4, s1=D1^D3, s2=D2^D4, s3=D3, s4=D4, s5=D5.
__device__ __forceinline__ int twiddle(int l) {
    int b0 = (l ^ (l >> 2) ^ (l >> 4)) & 1;
    int b1 = ((l >> 1) ^ (l >> 3)) & 1;
    int b2 = ((l >> 2) ^ (l >> 4)) & 1;
    return (l & 0x38) | (b2 << 2) | (b1 << 1) | b0;
}
__device__ __forceinline__ int fragoff(int R, int quad) {   // shorts
    return (((R << 2) | quad) ^ (R & 7)) << 3;
}

struct Ctx {
    int w, quad, l15, wm, wn, srow, scol;
    int offA[4], offB[8];
};

__device__ __forceinline__ Ctx make_ctx(int t) {
    Ctx c;
    const int lane = t & 63;
    c.w = t >> 6; c.quad = lane >> 4; c.l15 = lane & 15;
    c.wm = c.w >> 1; c.wn = c.w & 1;
    const int sl = twiddle(lane);
    c.srow = c.w * 32 + (sl >> 2);
    c.scol = (sl & 3) * 8;
    #pragma unroll
    for (int mt = 0; mt < 4; ++mt) { int R = c.wm * 64 + mt * 16 + c.l15; c.offA[mt] = fragoff(R, c.quad); }
    #pragma unroll
    for (int nt = 0; nt < 8; ++nt) { int R = c.wn * 128 + nt * 16 + c.l15; c.offB[nt] = fragoff(R, c.quad); }
    return c;
}

// Stage one 256x32 bf16 tile from a row-major [*][1024] plane; 2 gll16/thread.
__device__ __forceinline__ void stage2(const short* __restrict__ plane, int row0, int k0,
                                       short* tile, const Ctx& c) {
    const short* g0 = plane + (size_t)(row0 + c.srow) * 1024 + k0 + c.scol;
    gll16(g0, tile + c.w * 1024);
    gll16(g0 + (size_t)16 * 1024, tile + c.w * 1024 + 512);
}

__device__ __forceinline__ void mfma8x4(const short8v (&a)[4], const short8v (&bb)[8],
                                        float4v (&acc)[4][8]) {
    #pragma unroll
    for (int nt = 0; nt < 8; ++nt)
        #pragma unroll
        for (int mt = 0; mt < 4; ++mt)
            acc[mt][nt] = MFMA(a[mt], bb[nt], acc[mt][nt]);
}

// ---------------------------------------------------------------------------
// 256x256 3-phase K-step, all four streams via gll16 (g1, g2).
// Steady-state invariant entering P0: outstanding vmem = AlBl(tile s) = 4.
// ---------------------------------------------------------------------------
template<bool DS>
__device__ __forceinline__ void step_gg(const short* __restrict__ Ahp, const short* __restrict__ Alp,
                                        const short* __restrict__ Bhp, const short* __restrict__ Blp,
                                        int m0, int n0, int kn,
                                        const short* C0, const short* C1, const short* C2, const short* C3,
                                        short* N0, short* N1, short* N2, short* N3,
                                        const Ctx& c, float4v (&acc)[4][8]) {
    short8v ah[4], bh[8];
    #pragma unroll
    for (int mt = 0; mt < 4; ++mt) ah[mt] = *(const short8v*)(C0 + c.offA[mt]);
    #pragma unroll
    for (int nt = 0; nt < 8; ++nt) bh[nt] = *(const short8v*)(C2 + c.offB[nt]);
    if (DS) { stage2(Ahp, m0, kn, N0, c); stage2(Bhp, n0, kn, N2, c); VMCNT(4); }
    else    { VMCNT(0); }
    SB0(); BAR(); LGKM0(); SB0();
    PRIO(1); mfma8x4(ah, bh, acc); PRIO(0); SB0(); BAR();

    short8v al[4];
    #pragma unroll
    for (int mt = 0; mt < 4; ++mt) al[mt] = *(const short8v*)(C1 + c.offA[mt]);
    if (DS) { stage2(Alp, m0, kn, N1, c); stage2(Blp, n0, kn, N3, c); }
    SB0(); BAR(); LGKM0(); SB0();
    PRIO(1); mfma8x4(al, bh, acc); PRIO(0); SB0(); BAR();

    short8v bl[8];
    #pragma unroll
    for (int nt = 0; nt < 8; ++nt) bl[nt] = *(const short8v*)(C3 + c.offB[nt]);
    if (DS) { VMCNT(4); }   // drains AhBh(s+1) -> validates next P0; leaves AlBl(s+1)=4
    SB0(); BAR(); LGKM0(); SB0();
    PRIO(1); mfma8x4(ah, bl, acc); PRIO(0); SB0(); BAR();
}

__device__ __forceinline__ void core_gg(const short* __restrict__ Ahp, const short* __restrict__ Alp,
                                        const short* __restrict__ Bhp, const short* __restrict__ Blp,
                                        int m0, int n0, short* lds, const Ctx& c, float4v (&acc)[4][8]) {
    short *T00 = lds,         *T01 = lds + 8192,  *T02 = lds + 16384, *T03 = lds + 24576;
    short *T10 = lds + 32768, *T11 = lds + 40960, *T12 = lds + 49152, *T13 = lds + 57344;
    stage2(Ahp, m0, 0, T00, c); stage2(Bhp, n0, 0, T02, c);
    stage2(Alp, m0, 0, T01, c); stage2(Blp, n0, 0, T03, c);
    VMCNT(4); SB0(); BAR();
    #pragma unroll 1
    for (int it = 0; it < 15; ++it) {
        step_gg<true>(Ahp, Alp, Bhp, Blp, m0, n0, (2 * it + 1) * 32, T00, T01, T02, T03, T10, T11, T12, T13, c, acc);
        step_gg<true>(Ahp, Alp, Bhp, Blp, m0, n0, (2 * it + 2) * 32, T10, T11, T12, T13, T00, T01, T02, T03, c, acc);
    }
    step_gg<true >(Ahp, Alp, Bhp, Blp, m0, n0, 31 * 32, T00, T01, T02, T03, T10, T11, T12, T13, c, acc);
    step_gg<false>(Ahp, Alp, Bhp, Blp, m0, n0, 0,       T10, T11, T12, T13, T00, T01, T02, T03, c, acc);
}

// ---------------------------------------------------------------------------
// prep kernels
// ---------------------------------------------------------------------------
__global__ __launch_bounds__(256) void k_split(const float* __restrict__ src,
                                               short* __restrict__ h, short* __restrict__ l) {
    const size_t base = ((size_t)blockIdx.x * 256 + threadIdx.x) * 4;
    const float4 v = *(const float4*)(src + base);
    uint2 hh, ll;
    split4(v, hh, ll);
    *(uint2*)(h + base) = hh;
    *(uint2*)(l + base) = ll;
}

__global__ __launch_bounds__(256) void k_transpose(const float* __restrict__ keys,
                                                   short* __restrict__ th, short* __restrict__ tl) {
    __shared__ float T[32][33];
    const int t = threadIdx.x;
    const int b = blockIdx.z, d0 = blockIdx.x * 32, k0 = blockIdx.y * 32;
    const float* Kb = keys + (size_t)b * K_DIM * KD_DIM;
    const int ry = t >> 3, cx = (t & 7) * 4;
    const float4 v = *(const float4*)(Kb + (size_t)(k0 + ry) * KD_DIM + d0 + cx);
    T[ry][cx] = v.x; T[ry][cx + 1] = v.y; T[ry][cx + 2] = v.z; T[ry][cx + 3] = v.w;
    __syncthreads();
    float4 g;
    g.x = T[cx][ry]; g.y = T[cx + 1][ry]; g.z = T[cx + 2][ry]; g.w = T[cx + 3][ry];
    uint2 hh, ll;
    split4(g, hh, ll);
    const size_t o = (size_t)b * K_DIM * KD_DIM + (size_t)(d0 + ry) * K_DIM + k0 + cx;
    *(uint2*)(th + o) = hh;
    *(uint2*)(tl + o) = ll;
}

__global__ __launch_bounds__(256) void k_stats(const float* __restrict__ alpha,
                                               float* __restrict__ mx,
                                               float* __restrict__ il) {
    const int r = blockIdx.x;
    const int t = threadIdx.x;
    const float4 v = ((const float4*)(alpha + (size_t)r * K_DIM))[t];
    float m = fmaxf(fmaxf(v.x, v.y), fmaxf(v.z, v.w));
    #pragma unroll
    for (int o = 1; o < 64; o <<= 1) m = fmaxf(m, __shfl_xor(m, o, 64));
    __shared__ float redm[4];
    __shared__ float reds[4];
    const int wid = t >> 6;
    if ((t & 63) == 0) redm[wid] = m;
    __syncthreads();
    const float M = fmaxf(fmaxf(redm[0], redm[1]), fmaxf(redm[2], redm[3]));
    float s = expf(v.x - M) + expf(v.y - M) + expf(v.z - M) + expf(v.w - M);
    #pragma unroll
    for (int o = 1; o < 64; o <<= 1) s += __shfl_xor(s, o, 64);
    if ((t & 63) == 0) reds[wid] = s;
    __syncthreads();
    if (t == 0) {
        mx[r] = M;
        il[r] = 1.0f / (reds[0] + reds[1] + reds[2] + reds[3]);
    }
}

__global__ __launch_bounds__(256) void k_copy(const float4* __restrict__ src, float4* __restrict__ dst) {
    const size_t i = (size_t)blockIdx.x * 256 + threadIdx.x;
    dst[i] = src[i];
}

// ---------------------------------------------------------------------------
// GEMM1: TQ[m][n] = sum_k Q[m][k]*W[n][k], m = s*16+b. All streams pre-split.
// ---------------------------------------------------------------------------
__global__ __launch_bounds__(512, 2) void g1k(const short* __restrict__ Qh, const short* __restrict__ Ql,
                                              const short* __restrict__ Wh, const short* __restrict__ Wl,
                                              short* __restrict__ TQh, short* __restrict__ TQl) {
    __shared__ __align__(16) short lds[65536];
    const int t = threadIdx.x;
    const int m0 = blockIdx.y * 256, n0 = blockIdx.x * 256;
    const Ctx c = make_ctx(t);
    float4v acc[4][8] = {};
    core_gg(Qh, Ql, Wh, Wl, m0, n0, lds, c, acc);
    #pragma unroll
    for (int mt = 0; mt < 4; ++mt)
        #pragma unroll
        for (int reg = 0; reg < 4; ++reg) {
            const int m = m0 + c.wm * 64 + mt * 16 + c.quad * 4 + reg;
            const int s = m >> 4, bq = m & 15;
            short* th = TQh + (size_t)bq * 1048576 + (size_t)s * 1024;
            short* tl = TQl + (size_t)bq * 1048576 + (size_t)s * 1024;
            #pragma unroll
            for (int nt = 0; nt < 8; ++nt) {
                const int n = n0 + c.wn * 128 + nt * 16 + c.l15;
                const float x = acc[mt][nt][reg];
                const uint u = __float_as_uint(x);
                th[n] = (short)(u >> 16);
                const float r2 = x - __uint_as_float(u & 0xFFFF0000u);
                tl[n] = (short)(__float_as_uint(r2) >> 16);
            }
        }
}

// ---------------------------------------------------------------------------
// GEMM2 (per b): alpha[s][b][k] = sum_d TQ[b][s][d]*keys[b][k][d], + mask.
// ---------------------------------------------------------------------------
__global__ __launch_bounds__(512, 2) void g2k(const short* __restrict__ TQh, const short* __restrict__ TQl,
                                              const short* __restrict__ Kh, const short* __restrict__ Kl,
                                              const int* __restrict__ mask, float* __restrict__ alpha) {
    __shared__ __align__(16) short lds[65536];
    const int t = threadIdx.x;
    const int m0 = blockIdx.y * 256, n0 = blockIdx.x * 256, b = blockIdx.z;
    const Ctx c = make_ctx(t);
    float4v acc[4][8] = {};
    core_gg(TQh + (size_t)b * 1048576, TQl + (size_t)b * 1048576,
            Kh + (size_t)b * 1048576, Kl + (size_t)b * 1048576, m0, n0, lds, c, acc);
    int mk[8];
    #pragma unroll
    for (int nt = 0; nt < 8; ++nt)
        mk[nt] = mask[b * K_DIM + n0 + c.wn * 128 + nt * 16 + c.l15];
    #pragma unroll
    for (int mt = 0; mt < 4; ++mt)
        #pragma unroll
        for (int reg = 0; reg < 4; ++reg) {
            const int m = m0 + c.wm * 64 + mt * 16 + c.quad * 4 + reg;
            #pragma unroll
            for (int nt = 0; nt < 8; ++nt) {
                const int n = n0 + c.wn * 128 + nt * 16 + c.l15;
                alpha[((size_t)m * B_DIM + b) * K_DIM + n] = mk[nt] ? MASK_NEG : acc[mt][nt][reg];
            }
        }
}

// ---------------------------------------------------------------------------
// GEMM3 (per b): out[s][b][d] = sum_k P[s][k]*keys[b][k][d].
// A = P on the fly (reg-staged: global->reg in P0, exp+split+ds_write in P2);
// B via gll16 from pre-transposed KT streams.
// ---------------------------------------------------------------------------
__device__ __forceinline__ void writeA(const float4 (&va)[4], float Mv, float Lv,
                                       short* N0, short* N1, int ws0, int ws1) {
    uint2 h[4], l[4];
    #pragma unroll
    for (int i = 0; i < 4; ++i) {
        float4 p;
        p.x = __expf(va[i].x - Mv) * Lv;
        p.y = __expf(va[i].y - Mv) * Lv;
        p.z = __expf(va[i].z - Mv) * Lv;
        p.w = __expf(va[i].w - Mv) * Lv;
        split4(p, h[i], l[i]);
    }
    uint4v v0, v1;
    v0[0] = h[0].x; v0[1] = h[0].y; v0[2] = h[1].x; v0[3] = h[1].y;
    v1[0] = h[2].x; v1[1] = h[2].y; v1[2] = h[3].x; v1[3] = h[3].y;
    *(uint4v*)(N0 + ws0 * 8) = v0;
    *(uint4v*)(N0 + ws1 * 8) = v1;
    v0[0] = l[0].x; v0[1] = l[0].y; v0[2] = l[1].x; v0[3] = l[1].y;
    v1[0] = l[2].x; v1[1] = l[2].y; v1[2] = l[3].x; v1[3] = l[3].y;
    *(uint4v*)(N1 + ws0 * 8) = v0;
    *(uint4v*)(N1 + ws1 * 8) = v1;
}

template<bool DS>
__device__ __forceinline__ void step_g3(const float4* __restrict__ aP, int kn,
                                        const short* __restrict__ Bhp, const short* __restrict__ Blp, int n0,
                                        const short* C0, const short* C1, const short* C2, const short* C3,
                                        short* N0, short* N1, short* N2, short* N3,
                                        const Ctx& c, float Mv, float Lv, int ws0, int ws1,
                                        float4v (&acc)[4][8]) {
    short8v ah[4], bh[8];
    #pragma unroll
    for (int mt = 0; mt < 4; ++mt) ah[mt] = *(const short8v*)(C0 + c.offA[mt]);
    #pragma unroll
    for (int nt = 0; nt < 8; ++nt) bh[nt] = *(const short8v*)(C2 + c.offB[nt]);
    float4 va[4];
    if (DS) {
        #pragma unroll
        for (int i = 0; i < 4; ++i) va[i] = aP[kn / 4 + i];   // alpha(s+1) -> regs
        stage2(Bhp, n0, kn, N2, c);
    }
    SB0(); BAR(); LGKM0(); SB0();
    PRIO(1); mfma8x4(ah, bh, acc); PRIO(0); SB0(); BAR();

    short8v al[4];
    #pragma unroll
    for (int mt = 0; mt < 4; ++mt) al[mt] = *(const short8v*)(C1 + c.offA[mt]);
    if (DS) { stage2(Blp, n0, kn, N3, c); }
    SB0(); BAR(); LGKM0(); SB0();
    PRIO(1); mfma8x4(al, bh, acc); PRIO(0); SB0(); BAR();

    if (DS) { VMCNT(4); }   // drains Bl(s)+alpha; leaves Bh(s+1)2+Bl(s+1)2
    else    { VMCNT(0); }
    SB0(); BAR();
    short8v bl[8];
    #pragma unroll
    for (int nt = 0; nt < 8; ++nt) bl[nt] = *(const short8v*)(C3 + c.offB[nt]);
    LGKM0(); SB0();
    PRIO(1); mfma8x4(ah, bl, acc); PRIO(0);
    if (DS) {
        writeA(va, Mv, Lv, N0, N1, ws0, ws1);   // A(s+1) -> LDS (swizzled ds_write)
        LGKM0();
        VMCNT(2);   // drains Bh(s+1) -> validates next P0; leaves Bl(s+1)=2
    }
    SB0(); BAR();
}

__global__ __launch_bounds__(512, 2) void g3k(const float* __restrict__ alpha,
                                              const short* __restrict__ KTh, const short* __restrict__ KTl,
                                              const float* __restrict__ mx, const float* __restrict__ il,
                                              float* __restrict__ outk) {
    __shared__ __align__(16) short lds[65536];
    const int t = threadIdx.x;
    const int m0 = blockIdx.y * 256, n0 = blockIdx.x * 256, b = blockIdx.z;
    const Ctx c = make_ctx(t);
    const short* Bhp = KTh + (size_t)b * 1048576;
    const short* Blp = KTl + (size_t)b * 1048576;
    const int arow = t >> 1, ac = t & 1;
    const float4* aP = (const float4*)(alpha + ((size_t)(m0 + arow) * B_DIM + b) * K_DIM + ac * 16);
    const float Mv = mx[(size_t)(m0 + arow) * B_DIM + b];
    const float Lv = il[(size_t)(m0 + arow) * B_DIM + b];
    const int c0 = ac * 2;
    const int ws0 = ((arow << 2) | c0) ^ (arow & 7);
    const int ws1 = ((arow << 2) | (c0 + 1)) ^ (arow & 7);
    short *T00 = lds,         *T01 = lds + 8192,  *T02 = lds + 16384, *T03 = lds + 24576;
    short *T10 = lds + 32768, *T11 = lds + 40960, *T12 = lds + 49152, *T13 = lds + 57344;

    float4v acc[4][8] = {};
    // prologue: tile 0
    {
        float4 va[4];
        #pragma unroll
        for (int i = 0; i < 4; ++i) va[i] = aP[i];
        stage2(Bhp, n0, 0, T02, c);
        stage2(Blp, n0, 0, T03, c);
        VMCNT(4);                      // alpha(0) arrived; Bh0+Bl0 in flight
        writeA(va, Mv, Lv, T00, T01, ws0, ws1);
        LGKM0();
        VMCNT(2);                      // Bh(0) done; leaves Bl(0)=2
        SB0(); BAR();
    }
    #pragma unroll 1
    for (int it = 0; it < 15; ++it) {
        step_g3<true>(aP, (2 * it + 1) * 32, Bhp, Blp, n0, T00, T01, T02, T03, T10, T11, T12, T13, c, Mv, Lv, ws0, ws1, acc);
        step_g3<true>(aP, (2 * it + 2) * 32, Bhp, Blp, n0, T10, T11, T12, T13, T00, T01, T02, T03, c, Mv, Lv, ws0, ws1, acc);
    }
    step_g3<true >(aP, 31 * 32, Bhp, Blp, n0, T00, T01, T02, T03, T10, T11, T12, T13, c, Mv, Lv, ws0, ws1, acc);
    step_g3<false>(aP, 0,       Bhp, Blp, n0, T10, T11, T12, T13, T00, T01, T02, T03, c, Mv, Lv, ws0, ws1, acc);

    #pragma unroll
    for (int mt = 0; mt < 4; ++mt)
        #pragma unroll
        for (int reg = 0; reg < 4; ++reg) {
            const int m = m0 + c.wm * 64 + mt * 16 + c.quad * 4 + reg;
            #pragma unroll
            for (int nt = 0; nt < 8; ++nt) {
                const int n = n0 + c.wn * 128 + nt * 16 + c.l15;
                outk[((size_t)m * B_DIM + b) * KD_DIM + n] = acc[mt][nt][reg];
            }
        }
}

// ---------------------------------------------------------------------------
extern "C" void kernel_launch(void* const* d_in, const int* in_sizes, int n_in,
                              void* d_out, int out_size, void* d_ws, size_t ws_size,
                              hipStream_t stream) {
    const float* Q    = (const float*)d_in[0];   // (S, B, QD)
    const float* keys = (const float*)d_in[1];   // (B, K, KD)
    const int*   mask = (const int*)d_in[2];     // (B, K)
    const float* W    = (const float*)d_in[3];   // (KD, QD)

    float* out_att   = (float*)d_out;
    float* out_alpha = out_att + (size_t)S_DIM * B_DIM * KD_DIM;

    const size_t PLW    = 1048576;               // shorts per W stream (2 MiB)
    const size_t STREAM = (size_t)B_DIM * PLW;   // shorts per big stream (32 MiB)

    short *Wh, *Wl, *Qh, *Ql, *Khs, *Kls, *KTh, *KTl, *TQh, *TQl;
    float *mx, *il, *g3out;
    bool small_ws;
    char* ws = (char*)d_ws;

    if (ws_size >= ((size_t)261 << 20)) {
        // roomy workspace: everything in ws, no aliasing, no final copy
        small_ws = false;
        Wh  = (short*)ws;          Wl  = Wh + PLW;
        Qh  = Wl + PLW;            Ql  = Qh + STREAM;
        Khs = Ql + STREAM;         Kls = Khs + STREAM;
        KTh = Kls + STREAM;        KTl = KTh + STREAM;
        TQh = KTl + STREAM;        TQl = TQh + STREAM;
        mx  = (float*)(TQl + STREAM);
        il  = mx + S_DIM * B_DIM;
        g3out = out_att;
    } else {
        // proven-safe: ws use = 64 MiB + 128 KiB; d_out as sequenced scratch.
        //   att region:   Wh/Wl -> Kh/Kl -> KTh/KTl -> final copy dest
        //   alpha region: Qh/Ql until g2 overwrites it with real alpha
        small_ws = true;
        TQh = (short*)ws;          TQl = TQh + STREAM;
        mx  = (float*)((char*)ws + ((size_t)64 << 20));
        il  = mx + S_DIM * B_DIM;
        Wh  = (short*)out_att;     Wl  = Wh + PLW;
        Qh  = (short*)out_alpha;   Ql  = Qh + STREAM;
        Khs = (short*)out_att;     Kls = Khs + STREAM;
        KTh = Khs;                 KTl = Kls;    // sequential reuse after g2
        g3out = (float*)ws;                      // TQ region dead after g2
    }

    dim3 blk(256);
    dim3 blkg(512);

    k_split<<<dim3(1024), blk, 0, stream>>>(W, Wh, Wl);
    k_split<<<dim3(16384), blk, 0, stream>>>(Q, Qh, Ql);

    g1k<<<dim3(KD_DIM / 256, (S_DIM * B_DIM) / 256), blkg, 0, stream>>>(Qh, Ql, Wh, Wl, TQh, TQl);

    k_split<<<dim3(16384), blk, 0, stream>>>(keys, Khs, Kls);   // after g1 (aliases W in small-ws)

    g2k<<<dim3(K_DIM / 256, S_DIM / 256, B_DIM), blkg, 0, stream>>>(TQh, TQl, Khs, Kls, mask, out_alpha);

    k_transpose<<<dim3(32, 32, B_DIM), blk, 0, stream>>>(keys, KTh, KTl);  // after g2 (aliases K streams)

    k_stats<<<dim3(S_DIM * B_DIM), blk, 0, stream>>>(out_alpha, mx, il);

    g3k<<<dim3(KD_DIM / 256, S_DIM / 256, B_DIM), blkg, 0, stream>>>(out_alpha, KTh, KTl, mx, il, g3out);

    if (small_ws)
        k_copy<<<dim3((S_DIM * B_DIM * KD_DIM) / (4 * 256)), blk, 0, stream>>>((const float4*)g3out,
                                                                               (float4*)out_att);
}